// Round 7
// baseline (68.077 us; speedup 1.0000x reference)
//
#include <hip/hip_runtime.h>
#include <hip/hip_bf16.h>
#include <math.h>

// Problem constants (fixed by setup_inputs)
#define BS 2
#define NW 5
#define NS 5
#define NQ 5
#define FDIM 64
#define FH 21
#define FW 21
#define NPOS (FH*FW)            // 441
#define NIMG (BS*NW*(NS+NQ))    // 100
#define NQIMG 50
#define IMG_ELEMS (FDIM*NPOS)   // 28224
#define NY (NS*NPOS)            // 2205
#define QROWS 448               // 441 padded to 28*16
#define SROWS 2256              // 141 tiles: 138 used + 3 prefetch overrun
#define NYT 138                 // y-tiles of 16 (2208 rows)
#define YHALF 69                // y-tiles per half
#define NBLK 250
#define NBLK2 500               // sim blocks: (bid, y-half)
#define TILE_USH (16*FDIM)      // 1024 ushorts = 2 KB per tile

typedef __attribute__((ext_vector_type(8))) short short8;
typedef __attribute__((ext_vector_type(8))) unsigned short us8;
typedef __attribute__((ext_vector_type(4))) float f32x4;

static __device__ __forceinline__ unsigned short f2bf(float x) {
    union { float f; unsigned u; } v; v.f = x;
    unsigned r = v.u + 0x7fffu + ((v.u >> 16) & 1u);   // RNE; inputs finite
    return (unsigned short)(r >> 16);
}

static __device__ __forceinline__ void gload_lds16(const unsigned short* g, unsigned short* l) {
    __builtin_amdgcn_global_load_lds((const __attribute__((address_space(1))) void*)g,
                                     (__attribute__((address_space(3))) void*)l, 16, 0, 0);
}

// Insert d into sorted top-3 (a0>=a1>=a2): 3 independent VALU ops via med3
#define T3INS(d, a0, a1, a2) do { \
    float _n0 = fmaxf((d), (a0)); \
    float _n1 = __builtin_amdgcn_fmed3f((d), (a0), (a1)); \
    float _n2 = __builtin_amdgcn_fmed3f((d), (a1), (a2)); \
    (a0) = _n0; (a1) = _n1; (a2) = _n2; } while (0)

// Kernel A: L2-normalize per (img,pos); emit bf16 channel-contiguous.
// Query images -> Qn[qidx][QROWS][64] (compact, 50 imgs); support -> Sn[b*5+w][SROWS][64].
__global__ __launch_bounds__(256) void dn4_normalize(const float* __restrict__ fm,
                                                     const int* __restrict__ elabel,
                                                     unsigned short* __restrict__ Qn,
                                                     unsigned short* __restrict__ Sn,
                                                     float* __restrict__ out) {
    int gid = blockIdx.x * blockDim.x + threadIdx.x;
    if (gid < 50) {   // label pass-through: out[250+gid]
        int bb = gid / 25, rem = gid % 25, wq = rem / 5, qi = rem % 5;
        out[250 + gid] = (float)elabel[(bb * NW + wq) * (NS + NQ) + NS + qi];
    }
    if (gid < 240) {  // zero S pad rows: 10 mats x 3 rows x 8 us8
        int mat = gid / 24, rr = (gid % 24) >> 3, k8 = gid & 7;
        us8 zv = {0,0,0,0,0,0,0,0};
        *(us8*)(Sn + (size_t)mat * (SROWS * FDIM) + (size_t)(NY + rr) * FDIM + k8 * 8) = zv;
    }
    if (gid >= NIMG * NPOS) return;
    int img = gid / NPOS;
    int pos = gid - img * NPOS;
    const float* src = fm + (size_t)img * IMG_ELEMS + pos;
    float v[FDIM];
    float ss = 0.f;
#pragma unroll
    for (int c = 0; c < FDIM; ++c) {
        float x = src[(size_t)c * NPOS];
        v[c] = x;
        ss += x * x;
    }
    float rn = 1.0f / (sqrtf(ss) + 1e-12f);
    unsigned short tmp[FDIM];
#pragma unroll
    for (int c = 0; c < FDIM; ++c) tmp[c] = f2bf(v[c] * rn);

    int i10 = img % 10;
    if (i10 < NS) {
        int bw = img / 10;
        int y = i10 * NPOS + pos;
        us8* sd = (us8*)(Sn + (size_t)bw * (SROWS * FDIM) + (size_t)y * FDIM);
#pragma unroll
        for (int k = 0; k < 8; ++k) sd[k] = *(const us8*)(tmp + 8 * k);
    } else {
        int qidx = (img / 10) * NQ + (i10 - NS);
        us8* qd = (us8*)(Qn + (size_t)qidx * (QROWS * FDIM) + (size_t)pos * FDIM);
#pragma unroll
        for (int k = 0; k < 8; ++k) qd[k] = *(const us8*)(tmp + 8 * k);
    }
}

// Kernel B: 500 blocks = (bid, y-half); 448 threads = 7 waves (wave = xg).
// 2 blocks/CU -> two independent barrier domains per CU (stall overlap).
// S tiles staged once per block into LDS 3-ring via global_load_lds (pre-swizzled
// source, linear dest; XOR-swizzled ds_read), depth-2 counted vmcnt(2), per-tile
// s_barrier. TRANSPOSED MFMA (A=S rows, B=Q cols). Per-x top-3 written to ws.
__global__ __launch_bounds__(448, 4) void dn4_sim_mfma(const unsigned short* __restrict__ Qn,
                                                       const unsigned short* __restrict__ Sn,
                                                       float* __restrict__ gtop3) {
    __shared__ __align__(16) unsigned short sring[3][TILE_USH];   // 6 KB

    // m204 bijective chunked XCD swizzle over 500 logical units; consecutive units
    // (same bid, both halves) land on the same XCD -> shared S/Q in that L2.
    int orig = blockIdx.x;
    int xcd = orig & 7, idx = orig >> 3;
    const int qq = NBLK2 / 8, rr = NBLK2 % 8;   // 62, 4
    int unit = (xcd < rr ? xcd * (qq + 1) : rr * (qq + 1) + (xcd - rr) * qq) + idx;
    int bid = unit >> 1, yh = unit & 1;

    int w = bid % NW;
    int q = (bid / NW) % (NW * NQ);
    int b = bid / (NW * NW * NQ);
    int wq = q / NQ, qi = q % NQ;
    int qidx = (b * NW + wq) * NQ + qi;

    const unsigned short* qbase = Qn + (size_t)qidx * (QROWS * FDIM);
    const unsigned short* sbase = Sn + (size_t)(b * NW + w) * (SROWS * FDIM);

    int t = threadIdx.x;
    int lane = t & 63, xg = t >> 6;
    int lo16 = lane & 15, hi4 = lane >> 4;
    bool stageW = (xg == 0);

    // B fragments (Q): col = lo16 -> x = xt*16+lo16, k = hi4*8 .. +8
    short8 bq[4][2];
#pragma unroll
    for (int i = 0; i < 4; ++i) {
        int xt = xg * 4 + i;
        const unsigned short* qp = qbase + (size_t)(xt * 16 + lo16) * FDIM + hi4 * 8;
        bq[i][0] = *(const short8*)(qp);
        bq[i][1] = *(const short8*)(qp + 32);
    }

    float t0[4], t1[4], t2[4];
#pragma unroll
    for (int i = 0; i < 4; ++i) { t0[i] = -3e38f; t1[i] = -3e38f; t2[i] = -3e38f; }

    f32x4 z = {0.f, 0.f, 0.f, 0.f};

    int ybeg = yh * YHALF;

    // Stage source pre-swizzle: LDS linear [row][c] receives global [row][c ^ (row&7)]
    int stg0 = ((lane >> 3) * FDIM) + (((lane & 7) ^ ((lane >> 3) & 7)) * 8);
    // Swizzled read offsets (ushort units): col c -> read c ^ (lo16&7)
    int rd_a0 = lo16 * FDIM + ((hi4 ^ (lo16 & 7)) * 8);
    int rd_a1 = lo16 * FDIM + (((4 + hi4) ^ (lo16 & 7)) * 8);

    // Prologue: stage tiles ybeg, ybeg+1 into bufs 0,1
    if (stageW) {
        const unsigned short* g0 = sbase + (size_t)ybeg * TILE_USH + stg0;
        gload_lds16(g0, &sring[0][0]);
        gload_lds16(g0 + 8 * FDIM, &sring[0][0] + 8 * FDIM);
        const unsigned short* g1 = sbase + (size_t)(ybeg + 1) * TILE_USH + stg0;
        gload_lds16(g1, &sring[1][0]);
        gload_lds16(g1 + 8 * FDIM, &sring[1][0] + 8 * FDIM);
        asm volatile("s_waitcnt vmcnt(2)" ::: "memory");   // buf0 (and bq) landed
    }
    asm volatile("s_barrier" ::: "memory");

    int cur = 0, nxt2 = 2;
    for (int tt = 0; tt < YHALF; ++tt) {
        if (stageW) {   // stage tile tt+2 (overrun tiles allocated: SROWS=2256)
            const unsigned short* g = sbase + (size_t)(ybeg + tt + 2) * TILE_USH + stg0;
            unsigned short* d = &sring[nxt2][0];
            gload_lds16(g, d);
            gload_lds16(g + 8 * FDIM, d + 8 * FDIM);
        }
        const unsigned short* bufp = &sring[cur][0];
        short8 ca0 = *(const short8*)(bufp + rd_a0);
        short8 ca1 = *(const short8*)(bufp + rd_a1);
#pragma unroll
        for (int i = 0; i < 4; ++i) {
            f32x4 acc = __builtin_amdgcn_mfma_f32_16x16x32_bf16(ca0, bq[i][0], z, 0, 0, 0);
            acc = __builtin_amdgcn_mfma_f32_16x16x32_bf16(ca1, bq[i][1], acc, 0, 0, 0);
#pragma unroll
            for (int r = 0; r < 4; ++r) T3INS(acc[r], t0[i], t1[i], t2[i]);
        }
        if (stageW) asm volatile("s_waitcnt vmcnt(2)" ::: "memory");  // tile tt+1 ready
        asm volatile("s_barrier" ::: "memory");
        cur = (cur == 2) ? 0 : cur + 1;
        nxt2 = (nxt2 == 2) ? 0 : nxt2 + 1;
    }

    // Merge top-3 across the 4 y-quarter groups (hi4), then write to ws
#pragma unroll
    for (int i = 0; i < 4; ++i) {
        float a0 = t0[i], a1 = t1[i], a2 = t2[i];
#pragma unroll
        for (int mk = 16; mk <= 32; mk <<= 1) {
            float c0 = __shfl_xor(a0, mk, 64);
            float c1 = __shfl_xor(a1, mk, 64);
            float c2 = __shfl_xor(a2, mk, 64);
            T3INS(c0, a0, a1, a2);
            T3INS(c1, a0, a1, a2);
            T3INS(c2, a0, a1, a2);
        }
        if (hi4 == 0) {
            int x = (xg * 4 + i) * 16 + lo16;
            float* dst = gtop3 + ((size_t)(bid * QROWS + x) * 2 + yh) * 3;
            dst[0] = a0; dst[1] = a1; dst[2] = a2;
        }
    }
}

// Kernel C: merge the two y-halves per (bid,x), sum top-3, block-reduce -> out[bid]
__global__ __launch_bounds__(448) void dn4_merge(const float* __restrict__ gtop3,
                                                 float* __restrict__ out) {
    __shared__ float red[7];
    int bid = blockIdx.x;
    int t = threadIdx.x, lane = t & 63, wv = t >> 6;
    const float* p = gtop3 + (size_t)(bid * QROWS + t) * 6;
    float a0 = p[0], a1 = p[1], a2 = p[2];
    float b0 = p[3], b1 = p[4], b2 = p[5];
    T3INS(b0, a0, a1, a2);
    T3INS(b1, a0, a1, a2);
    T3INS(b2, a0, a1, a2);
    float s = (t < NPOS) ? (a0 + a1 + a2) : 0.f;
#pragma unroll
    for (int off = 32; off >= 1; off >>= 1) s += __shfl_xor(s, off, 64);
    if (lane == 0) red[wv] = s;
    __syncthreads();
    if (t == 0) {
        float tot = 0.f;
#pragma unroll
        for (int i = 0; i < 7; ++i) tot += red[i];
        out[bid] = tot;
    }
}

extern "C" void kernel_launch(void* const* d_in, const int* in_sizes, int n_in,
                              void* d_out, int out_size, void* d_ws, size_t ws_size,
                              hipStream_t stream) {
    const float* fm     = (const float*)d_in[0];
    const int*   elabel = (const int*)d_in[1];
    float* out = (float*)d_out;

    unsigned short* Qn = (unsigned short*)d_ws;                    // 50*448*64 ush = 2.87 MB
    unsigned short* Sn = Qn + (size_t)NQIMG * QROWS * FDIM;        // 10*2256*64 ush = 2.89 MB
    float* gtop3 = (float*)(Sn + (size_t)10 * SROWS * FDIM);       // 250*448*6 f32 = 2.69 MB

    int nthreads = NIMG * NPOS;
    dn4_normalize<<<(nthreads + 255) / 256, 256, 0, stream>>>(fm, elabel, Qn, Sn, out);
    dn4_sim_mfma<<<NBLK2, 448, 0, stream>>>(Qn, Sn, gtop3);
    dn4_merge<<<NBLK, 448, 0, stream>>>(gtop3, out);
}

// Round 8
// 67.338 us; speedup vs baseline: 1.0110x; 1.0110x over previous
//
#include <hip/hip_runtime.h>
#include <hip/hip_bf16.h>
#include <math.h>

// Problem constants (fixed by setup_inputs)
#define BS 2
#define NW 5
#define NS 5
#define NQ 5
#define FDIM 64
#define FH 21
#define FW 21
#define NPOS (FH*FW)            // 441
#define NIMG (BS*NW*(NS+NQ))    // 100
#define NQIMG 50
#define IMG_ELEMS (FDIM*NPOS)   // 28224
#define NY (NS*NPOS)            // 2205
#define QROWS 448               // 441 padded to 28*16
#define SROWS 2240              // 140 tiles of 16 rows; rows 2205..2239 zeroed
#define NT_Q 35                 // y-tiles per quarter
#define NBLK 250
#define NBLK_SIM 1000           // (bid, y-quarter)
#define TILE_USH (16*FDIM)      // 1024 ushorts = 2 KB per tile

typedef __attribute__((ext_vector_type(8))) short short8;
typedef __attribute__((ext_vector_type(8))) unsigned short us8;
typedef __attribute__((ext_vector_type(4))) float f32x4;

static __device__ __forceinline__ unsigned short f2bf(float x) {
    union { float f; unsigned u; } v; v.f = x;
    unsigned r = v.u + 0x7fffu + ((v.u >> 16) & 1u);   // RNE; inputs finite
    return (unsigned short)(r >> 16);
}

static __device__ __forceinline__ void gload_lds16(const unsigned short* g, unsigned short* l) {
    __builtin_amdgcn_global_load_lds((const __attribute__((address_space(1))) void*)g,
                                     (__attribute__((address_space(3))) void*)l, 16, 0, 0);
}

// Insert d into sorted top-3 (a0>=a1>=a2): 3 independent VALU ops via med3
#define T3INS(d, a0, a1, a2) do { \
    float _n0 = fmaxf((d), (a0)); \
    float _n1 = __builtin_amdgcn_fmed3f((d), (a0), (a1)); \
    float _n2 = __builtin_amdgcn_fmed3f((d), (a1), (a2)); \
    (a0) = _n0; (a1) = _n1; (a2) = _n2; } while (0)

// Kernel A: L2-normalize per (img,pos); emit bf16 channel-contiguous.
// Query images -> Qn[qidx][QROWS][64] (compact); support -> Sn[b*5+w][SROWS][64].
__global__ __launch_bounds__(256) void dn4_normalize(const float* __restrict__ fm,
                                                     const int* __restrict__ elabel,
                                                     unsigned short* __restrict__ Qn,
                                                     unsigned short* __restrict__ Sn,
                                                     float* __restrict__ out) {
    int gid = blockIdx.x * blockDim.x + threadIdx.x;
    if (gid < 50) {   // label pass-through: out[250+gid]
        int bb = gid / 25, rem = gid % 25, wq = rem / 5, qi = rem % 5;
        out[250 + gid] = (float)elabel[(bb * NW + wq) * (NS + NQ) + NS + qi];
    }
    if (gid < 2800) { // zero S pad rows 2205..2239: 10 mats x 35 rows x 8 us8
        int mat = gid / 280, rem = gid % 280, rr = rem >> 3, k8 = rem & 7;
        us8 zv = {0,0,0,0,0,0,0,0};
        *(us8*)(Sn + (size_t)mat * (SROWS * FDIM) + (size_t)(NY + rr) * FDIM + k8 * 8) = zv;
    }
    if (gid >= NIMG * NPOS) return;
    int img = gid / NPOS;
    int pos = gid - img * NPOS;
    const float* src = fm + (size_t)img * IMG_ELEMS + pos;
    float v[FDIM];
    float ss = 0.f;
#pragma unroll
    for (int c = 0; c < FDIM; ++c) {
        float x = src[(size_t)c * NPOS];
        v[c] = x;
        ss += x * x;
    }
    float rn = 1.0f / (sqrtf(ss) + 1e-12f);
    unsigned short tmp[FDIM];
#pragma unroll
    for (int c = 0; c < FDIM; ++c) tmp[c] = f2bf(v[c] * rn);

    int i10 = img % 10;
    if (i10 < NS) {
        int bw = img / 10;
        int y = i10 * NPOS + pos;
        us8* sd = (us8*)(Sn + (size_t)bw * (SROWS * FDIM) + (size_t)y * FDIM);
#pragma unroll
        for (int k = 0; k < 8; ++k) sd[k] = *(const us8*)(tmp + 8 * k);
    } else {
        int qidx = (img / 10) * NQ + (i10 - NS);
        us8* qd = (us8*)(Qn + (size_t)qidx * (QROWS * FDIM) + (size_t)pos * FDIM);
#pragma unroll
        for (int k = 0; k < 8; ++k) qd[k] = *(const us8*)(tmp + 8 * k);
    }
}

// Kernel B: 1000 blocks = (bid, y-quarter); 448 threads = 7 waves (wave = xg).
// Entire 35-tile S-slice (70 KB) staged ONCE into LDS cooperatively via
// global_load_lds (pre-swizzled source, linear dest), then a barrier-free
// compute loop: XOR-swizzled ds_read + transposed MFMA + med3 top-3.
// 2 blocks/CU resident. Per-(x,quarter) top-3 written to ws; merged by kernel C.
__global__ __launch_bounds__(448, 4) void dn4_sim_mfma(const unsigned short* __restrict__ Qn,
                                                       const unsigned short* __restrict__ Sn,
                                                       float* __restrict__ gtop3) {
    __shared__ __align__(16) unsigned short stile[NT_Q][TILE_USH];   // 71,680 B

    // XCD swizzle (1000 % 8 == 0 -> simple bijective form): consecutive units
    // (same bid, 4 quarters; neighboring bids) share Q/S in one XCD's L2.
    int orig = blockIdx.x;
    int unit = (orig & 7) * (NBLK_SIM / 8) + (orig >> 3);
    int bid = unit >> 2, yq = unit & 3;

    int w = bid % NW;
    int q = (bid / NW) % (NW * NQ);
    int b = bid / (NW * NW * NQ);
    int wq = q / NQ, qi = q % NQ;
    int qidx = (b * NW + wq) * NQ + qi;

    const unsigned short* qbase = Qn + (size_t)qidx * (QROWS * FDIM);
    const unsigned short* sbase = Sn + (size_t)(b * NW + w) * (SROWS * FDIM);

    int t = threadIdx.x;
    int lane = t & 63, xg = t >> 6;
    int lo16 = lane & 15, hi4 = lane >> 4;

    // Stage source pre-swizzle: LDS linear [row][c] receives global [row][c ^ (row&7)]
    // (c = 16B unit within a 128B row; chunk = 8 rows, so row&7 == lane>>3)
    int stg0 = ((lane >> 3) * FDIM) + (((lane & 7) ^ ((lane >> 3) & 7)) * 8);
    int tbase = yq * NT_Q;

    // Cooperative stage: 70 half-tile chunks over 7 waves (10 gload_lds each)
    for (int i = xg; i < 2 * NT_Q; i += 7) {
        int tile = i >> 1, h = i & 1;
        gload_lds16(sbase + (size_t)(tbase + tile) * TILE_USH + h * (8 * FDIM) + stg0,
                    &stile[tile][h * (8 * FDIM)]);
    }

    // B fragments (Q): col = lo16 -> x = xt*16+lo16, k = hi4*8 .. +8
    short8 bq[4][2];
#pragma unroll
    for (int i = 0; i < 4; ++i) {
        int xt = xg * 4 + i;
        const unsigned short* qp = qbase + (size_t)(xt * 16 + lo16) * FDIM + hi4 * 8;
        bq[i][0] = *(const short8*)(qp);
        bq[i][1] = *(const short8*)(qp + 32);
    }

    asm volatile("s_waitcnt vmcnt(0)" ::: "memory");
    __syncthreads();   // the ONLY barrier

    float t0[4], t1[4], t2[4];
#pragma unroll
    for (int i = 0; i < 4; ++i) { t0[i] = -3e38f; t1[i] = -3e38f; t2[i] = -3e38f; }

    f32x4 z = {0.f, 0.f, 0.f, 0.f};

    // Swizzled read offsets (ushort units): col c -> read c ^ (lo16&7)
    int rd_a0 = lo16 * FDIM + ((hi4 ^ (lo16 & 7)) * 8);
    int rd_a1 = lo16 * FDIM + (((4 + hi4) ^ (lo16 & 7)) * 8);

    // Barrier-free compute loop, 1-deep LDS prefetch
    short8 ca0 = *(const short8*)(&stile[0][0] + rd_a0);
    short8 ca1 = *(const short8*)(&stile[0][0] + rd_a1);
    for (int tt = 0; tt < NT_Q; ++tt) {
        short8 na0 = ca0, na1 = ca1;
        if (tt + 1 < NT_Q) {
            na0 = *(const short8*)(&stile[tt + 1][0] + rd_a0);
            na1 = *(const short8*)(&stile[tt + 1][0] + rd_a1);
        }
#pragma unroll
        for (int i = 0; i < 4; ++i) {
            f32x4 acc = __builtin_amdgcn_mfma_f32_16x16x32_bf16(ca0, bq[i][0], z, 0, 0, 0);
            acc = __builtin_amdgcn_mfma_f32_16x16x32_bf16(ca1, bq[i][1], acc, 0, 0, 0);
#pragma unroll
            for (int r = 0; r < 4; ++r) T3INS(acc[r], t0[i], t1[i], t2[i]);
        }
        ca0 = na0; ca1 = na1;
    }

    // Merge top-3 across the 4 y-quarter lane-groups (hi4), write to ws
#pragma unroll
    for (int i = 0; i < 4; ++i) {
        float a0 = t0[i], a1 = t1[i], a2 = t2[i];
#pragma unroll
        for (int mk = 16; mk <= 32; mk <<= 1) {
            float c0 = __shfl_xor(a0, mk, 64);
            float c1 = __shfl_xor(a1, mk, 64);
            float c2 = __shfl_xor(a2, mk, 64);
            T3INS(c0, a0, a1, a2);
            T3INS(c1, a0, a1, a2);
            T3INS(c2, a0, a1, a2);
        }
        if (hi4 == 0) {
            int x = (xg * 4 + i) * 16 + lo16;
            float* dst = gtop3 + ((size_t)(bid * QROWS + x) * 4 + yq) * 3;
            dst[0] = a0; dst[1] = a1; dst[2] = a2;
        }
    }
}

// Kernel C: merge the 4 y-quarters per (bid,x), sum top-3, block-reduce -> out[bid]
__global__ __launch_bounds__(448) void dn4_merge(const float* __restrict__ gtop3,
                                                 float* __restrict__ out) {
    __shared__ float red[7];
    int bid = blockIdx.x;
    int t = threadIdx.x, lane = t & 63, wv = t >> 6;
    const float4* p = (const float4*)(gtop3 + (size_t)(bid * QROWS + t) * 12);
    float4 v0 = p[0], v1 = p[1], v2 = p[2];
    float a0 = v0.x, a1 = v0.y, a2 = v0.z;
    T3INS(v0.w, a0, a1, a2);
    T3INS(v1.x, a0, a1, a2);
    T3INS(v1.y, a0, a1, a2);
    T3INS(v1.z, a0, a1, a2);
    T3INS(v1.w, a0, a1, a2);
    T3INS(v2.x, a0, a1, a2);
    T3INS(v2.y, a0, a1, a2);
    T3INS(v2.z, a0, a1, a2);
    T3INS(v2.w, a0, a1, a2);
    float s = (t < NPOS) ? (a0 + a1 + a2) : 0.f;
#pragma unroll
    for (int off = 32; off >= 1; off >>= 1) s += __shfl_xor(s, off, 64);
    if (lane == 0) red[wv] = s;
    __syncthreads();
    if (t == 0) {
        float tot = 0.f;
#pragma unroll
        for (int i = 0; i < 7; ++i) tot += red[i];
        out[bid] = tot;
    }
}

extern "C" void kernel_launch(void* const* d_in, const int* in_sizes, int n_in,
                              void* d_out, int out_size, void* d_ws, size_t ws_size,
                              hipStream_t stream) {
    const float* fm     = (const float*)d_in[0];
    const int*   elabel = (const int*)d_in[1];
    float* out = (float*)d_out;

    unsigned short* Qn = (unsigned short*)d_ws;                    // 50*448*64 ush  = 2.87 MB
    unsigned short* Sn = Qn + (size_t)NQIMG * QROWS * FDIM;        // 10*2240*64 ush = 2.87 MB
    float* gtop3 = (float*)(Sn + (size_t)10 * SROWS * FDIM);       // 250*448*12 f32 = 5.38 MB

    int nthreads = NIMG * NPOS;
    dn4_normalize<<<(nthreads + 255) / 256, 256, 0, stream>>>(fm, elabel, Qn, Sn, out);
    dn4_sim_mfma<<<NBLK_SIM, 448, 0, stream>>>(Qn, Sn, gtop3);
    dn4_merge<<<NBLK, 448, 0, stream>>>(gtop3, out);
}